// Round 6
// baseline (452.996 us; speedup 1.0000x reference)
//
#include <hip/hip_runtime.h>
#include <stdint.h>

// Problem: B=32, T=128, C=64, DIN=DOUT=32, 4 gates.
#define T_STEPS 128
#define C_CH    64
#define HS      40   // H plane row stride in shorts (80 B: 16B-aligned rows, 2-way banks)

using frag_ab = __attribute__((ext_vector_type(8))) short;  // 8 bf16
using frag_cd = __attribute__((ext_vector_type(4))) float;  // 4 fp32 acc
typedef __attribute__((ext_vector_type(4))) uint32_t u32x4;

// low short = u0[31:16], high short = u1[31:16]
__device__ __forceinline__ uint32_t pack_hi16(uint32_t u0, uint32_t u1) {
  return __builtin_amdgcn_perm(u1, u0, 0x07060302u);
}

__device__ __forceinline__ float fast_sigmoid(float v) {
  return __builtin_amdgcn_rcpf(1.0f + __expf(-v));
}
__device__ __forceinline__ float fast_tanh(float v) {
  return fmaf(2.0f, __builtin_amdgcn_rcpf(1.0f + __expf(-2.0f * v)), -1.0f);
}

// async global->LDS DMA, 16B per lane, dest = wave-uniform base + lane*16
__device__ __forceinline__ void async_load16(const float* g, void* l) {
  __builtin_amdgcn_global_load_lds((const __attribute__((address_space(1))) void*)g,
                                   (__attribute__((address_space(3))) void*)l, 16, 0, 0);
}

struct Frag2 { frag_ab hi, lo; };

// fp32x8 -> (hi bf16 x8, lo bf16 x8); hi = trunc16(f), lo = trunc16(f - hi)
__device__ __forceinline__ Frag2 split8(float4 a, float4 b) {
  uint32_t u0 = __float_as_uint(a.x), u1 = __float_as_uint(a.y);
  uint32_t u2 = __float_as_uint(a.z), u3 = __float_as_uint(a.w);
  uint32_t u4 = __float_as_uint(b.x), u5 = __float_as_uint(b.y);
  uint32_t u6 = __float_as_uint(b.z), u7 = __float_as_uint(b.w);
  uint32_t r0 = __float_as_uint(a.x - __uint_as_float(u0 & 0xFFFF0000u));
  uint32_t r1 = __float_as_uint(a.y - __uint_as_float(u1 & 0xFFFF0000u));
  uint32_t r2 = __float_as_uint(a.z - __uint_as_float(u2 & 0xFFFF0000u));
  uint32_t r3 = __float_as_uint(a.w - __uint_as_float(u3 & 0xFFFF0000u));
  uint32_t r4 = __float_as_uint(b.x - __uint_as_float(u4 & 0xFFFF0000u));
  uint32_t r5 = __float_as_uint(b.y - __uint_as_float(u5 & 0xFFFF0000u));
  uint32_t r6 = __float_as_uint(b.z - __uint_as_float(u6 & 0xFFFF0000u));
  uint32_t r7 = __float_as_uint(b.w - __uint_as_float(u7 & 0xFFFF0000u));
  union { u32x4 v; frag_ab f; } H, L;
  H.v[0] = pack_hi16(u0, u1); H.v[1] = pack_hi16(u2, u3);
  H.v[2] = pack_hi16(u4, u5); H.v[3] = pack_hi16(u6, u7);
  L.v[0] = pack_hi16(r0, r1); L.v[1] = pack_hi16(r2, r3);
  L.v[2] = pack_hi16(r4, r5); L.v[3] = pack_hi16(r6, r7);
  Frag2 o; o.hi = H.f; o.lo = L.f; return o;
}

// Grid: 512 blocks = qq*64 + c, qq in 0..7 (4 batches each). All 8 qq-blocks of
// channel c land on one XCD (blockIdx mod 8 = c mod 8), so the 8x redundant
// weight reads are served by that XCD's L2. 2 blocks/CU -> 16 waves/CU: the
// first real inter-block TLP of this session (grid=256 capped all prior rounds
// at 1 block/CU).
// Block: 512 threads = 8 waves; frag-row map (g=frag_n&3, i=4w+(frag_n>>2))
// puts all 4 gates of output i in one lane's acc[0..3] (no gate exchange).
// Weights: zero intra-block reuse -> NO LDS staging; each lane loads exactly
// its 8-float fragment slices, double-buffered in 32 VGPRs. The per-step
// vmcnt(0)+barrier enforces distance-1 structurally (memory clobber: loads
// cannot sink past the barrier), so regalloc can't collapse the pipeline
// (R4/R5 failure). LDS holds only x (1KB DMA ring) + h (pre-split bf16).
__global__ void __launch_bounds__(512, 4)
lstm_kernel(const float* __restrict__ x, const float* __restrict__ xOps,
            const float* __restrict__ hOps, float* __restrict__ out) {
  __shared__ __align__(16) float Bx[2][16][32];   // 4 KiB; rows 8..15 stay 0
  __shared__ __align__(16) short Hhi[2][16][HS];  // 2.5 KiB; rows 4..15 stay 0
  __shared__ __align__(16) short Hlo[2][16][HS];  // 2.5 KiB

  const int tid    = threadIdx.x;
  const int c      = blockIdx.x & 63;
  const int qq     = blockIdx.x >> 6;     // batch-eighth, 4 batches
  const int w      = tid >> 6;
  const int lane   = tid & 63;
  const int frag_n = lane & 15;           // batch col (valid < 4)
  const int quad   = lane >> 4;

  // A fragment source: weight row (g=frag_n&3, i=4w+(frag_n>>2)), k=quad*8..+8
  const int g  = frag_n & 3;
  const int iw = 4 * w + (frag_n >> 2);
  const size_t woff = ((size_t)g * T_STEPS * C_CH + c) * 1024
                    + (size_t)iw * 32 + quad * 8;
  const float* pwx = xOps + woff;   // points at step 0
  const float* pwh = hOps + woff;

  // x DMA (wave 7): lane l -> LDS row l>>3, slot l&7; source slot pre-swizzled
  // by ^(row&7) so the read-side XOR (rule #21 both-sides) sees linear data.
  // Rows 4..7 duplicate batches 0..3 (pad cols, never stored).
  const int xrow = lane >> 3;
  const float* xsrc = x + ((size_t)(qq * 4 + (xrow & 3)) * T_STEPS * C_CH + c) * 32
                        + (((lane & 7) ^ (xrow & 7)) << 2);

  // Zero x pad rows + h planes (h(0)=0; pad rows stay 0 forever).
  for (int idx = tid; idx < 2 * 16 * 32; idx += 512) ((float*)Bx)[idx] = 0.f;
  for (int idx = tid; idx < 2 * 16 * HS / 2; idx += 512) {
    ((uint32_t*)Hhi)[idx] = 0u; ((uint32_t*)Hlo)[idx] = 0u;
  }
  asm volatile("s_waitcnt lgkmcnt(0)\n\ts_barrier" ::: "memory");

  // ---- prologue: step 0 into slot A (regs) + Bx[0] (DMA) ----
  float4 wvA[4], wvB[4];
  wvA[0] = ((const float4*)pwx)[0]; wvA[1] = ((const float4*)pwx)[1];
  wvA[2] = ((const float4*)pwh)[0]; wvA[3] = ((const float4*)pwh)[1];
  if (w == 7) async_load16(xsrc, &Bx[0][0][0]);

  const int bs0 = (((quad << 1) ^ (frag_n & 7)) << 2);        // x read offsets
  const int bs1 = ((((quad << 1) | 1) ^ (frag_n & 7)) << 2);
  const int hrd = quad * 8;        // h-frag read col (shorts; 16B aligned)
  const int iq  = 4 * w + quad;    // this lane's output dim
  float c_state = 0.0f;

  // One step: barrier -> prefetch T+1 into NXT/Bx[PAR^1] -> consume CUR/Bx[PAR]
  // -> gates -> h write to H[PAR^1].  PAR = T&1 (compile-time at each call).
#define STEP(T, CUR, NXT, PAR)                                                  \
  do {                                                                          \
    /* drain: step T's A-loads+x-DMA (issued last segment) + h-writes */        \
    asm volatile("s_waitcnt vmcnt(0) lgkmcnt(0)\n\ts_barrier" ::: "memory");    \
    if ((T) + 1 < T_STEPS) {  /* issue early: in flight across this segment */  \
      pwx += C_CH * 1024;                                                       \
      NXT[0] = ((const float4*)pwx)[0]; NXT[1] = ((const float4*)pwx)[1];       \
      pwh += C_CH * 1024;                                                       \
      NXT[2] = ((const float4*)pwh)[0]; NXT[3] = ((const float4*)pwh)[1];       \
      if (w == 7) {                                                             \
        xsrc += C_CH * 32;                                                      \
        async_load16(xsrc, &Bx[(PAR) ^ 1][0][0]);                               \
      }                                                                         \
    }                                                                           \
    Frag2 A0 = split8(CUR[0], CUR[1]);   /* xOps rows */                        \
    Frag2 A1 = split8(CUR[2], CUR[3]);   /* hOps rows */                        \
    const float* Bp = &Bx[PAR][frag_n][0];                                      \
    Frag2 BX = split8(*(const float4*)(Bp + bs0), *(const float4*)(Bp + bs1));  \
    frag_cd ax = {0.f, 0.f, 0.f, 0.f};                                          \
    ax = __builtin_amdgcn_mfma_f32_16x16x32_bf16(A0.hi, BX.hi, ax, 0, 0, 0);    \
    ax = __builtin_amdgcn_mfma_f32_16x16x32_bf16(A0.hi, BX.lo, ax, 0, 0, 0);    \
    ax = __builtin_amdgcn_mfma_f32_16x16x32_bf16(A0.lo, BX.hi, ax, 0, 0, 0);    \
    const frag_ab bh = *(const frag_ab*)&Hhi[PAR][frag_n][hrd];                 \
    const frag_ab bl = *(const frag_ab*)&Hlo[PAR][frag_n][hrd];                 \
    frag_cd ah = {0.f, 0.f, 0.f, 0.f};                                          \
    ah = __builtin_amdgcn_mfma_f32_16x16x32_bf16(A1.hi, bh, ah, 0, 0, 0);       \
    ah = __builtin_amdgcn_mfma_f32_16x16x32_bf16(A1.hi, bl, ah, 0, 0, 0);       \
    ah = __builtin_amdgcn_mfma_f32_16x16x32_bf16(A1.lo, bh, ah, 0, 0, 0);       \
    const float ig = fast_sigmoid(ax[0] + ah[0]);                               \
    const float fg = fast_sigmoid(ax[1] + ah[1]);                               \
    const float gg = fast_tanh(ax[2] + ah[2]);                                  \
    const float og = fast_sigmoid(ax[3] + ah[3]);                               \
    c_state = fg * c_state + ig * gg;                                           \
    const float hval = og * fast_tanh(c_state);                                 \
    if ((T) == T_STEPS - 1) {                                                   \
      if (frag_n < 4)                                                           \
        out[((size_t)(qq * 4 + frag_n) * C_CH + c) * 32 + iq] = hval;           \
    } else if (frag_n < 4) {                                                    \
      const uint32_t uh = __float_as_uint(hval);                                \
      const float    rh = hval - __uint_as_float(uh & 0xFFFF0000u);             \
      Hhi[(PAR) ^ 1][frag_n][iq] = (short)(uh >> 16);                           \
      Hlo[(PAR) ^ 1][frag_n][iq] = (short)(__float_as_uint(rh) >> 16);          \
    }                                                                           \
  } while (0)

  for (int tb = 0; tb < T_STEPS; tb += 2) {
    STEP(tb,     wvA, wvB, 0);
    STEP(tb + 1, wvB, wvA, 1);
  }
#undef STEP
}

extern "C" void kernel_launch(void* const* d_in, const int* in_sizes, int n_in,
                              void* d_out, int out_size, void* d_ws, size_t ws_size,
                              hipStream_t stream) {
  const float* x    = (const float*)d_in[0];
  const float* xOps = (const float*)d_in[1];
  const float* hOps = (const float*)d_in[2];
  lstm_kernel<<<dim3(512), dim3(512), 0, stream>>>(x, xOps, hOps, (float*)d_out);
}

// Round 7
// 399.075 us; speedup vs baseline: 1.1351x; 1.1351x over previous
//
#include <hip/hip_runtime.h>
#include <stdint.h>

// Problem: B=32, T=128, C=64, DIN=DOUT=32, 4 gates.
#define T_STEPS 128
#define C_CH    64
#define HS      40   // H plane row stride in shorts (80 B: 16B-aligned, banks covered)

using frag_ab = __attribute__((ext_vector_type(8))) short;  // 8 bf16
using frag_cd = __attribute__((ext_vector_type(4))) float;  // 4 fp32 acc
typedef __attribute__((ext_vector_type(4))) uint32_t u32x4;

// low short = u0[31:16], high short = u1[31:16]
__device__ __forceinline__ uint32_t pack_hi16(uint32_t u0, uint32_t u1) {
  return __builtin_amdgcn_perm(u1, u0, 0x07060302u);
}

__device__ __forceinline__ float fast_sigmoid(float v) {
  return __builtin_amdgcn_rcpf(1.0f + __expf(-v));
}
__device__ __forceinline__ float fast_tanh(float v) {
  return fmaf(2.0f, __builtin_amdgcn_rcpf(1.0f + __expf(-2.0f * v)), -1.0f);
}

// async global->LDS DMA, 16B per lane, dest = wave-uniform base + lane*16
__device__ __forceinline__ void async_load16(const float* g, void* l) {
  __builtin_amdgcn_global_load_lds((const __attribute__((address_space(1))) void*)g,
                                   (__attribute__((address_space(3))) void*)l, 16, 0, 0);
}

struct Frag2 { frag_ab hi, lo; };

// fp32x8 -> (hi bf16 x8, lo bf16 x8); hi = trunc16(f), lo = trunc16(f - hi)
__device__ __forceinline__ Frag2 split8(float4 a, float4 b) {
  uint32_t u0 = __float_as_uint(a.x), u1 = __float_as_uint(a.y);
  uint32_t u2 = __float_as_uint(a.z), u3 = __float_as_uint(a.w);
  uint32_t u4 = __float_as_uint(b.x), u5 = __float_as_uint(b.y);
  uint32_t u6 = __float_as_uint(b.z), u7 = __float_as_uint(b.w);
  uint32_t r0 = __float_as_uint(a.x - __uint_as_float(u0 & 0xFFFF0000u));
  uint32_t r1 = __float_as_uint(a.y - __uint_as_float(u1 & 0xFFFF0000u));
  uint32_t r2 = __float_as_uint(a.z - __uint_as_float(u2 & 0xFFFF0000u));
  uint32_t r3 = __float_as_uint(a.w - __uint_as_float(u3 & 0xFFFF0000u));
  uint32_t r4 = __float_as_uint(b.x - __uint_as_float(u4 & 0xFFFF0000u));
  uint32_t r5 = __float_as_uint(b.y - __uint_as_float(u5 & 0xFFFF0000u));
  uint32_t r6 = __float_as_uint(b.z - __uint_as_float(u6 & 0xFFFF0000u));
  uint32_t r7 = __float_as_uint(b.w - __uint_as_float(u7 & 0xFFFF0000u));
  union { u32x4 v; frag_ab f; } H, L;
  H.v[0] = pack_hi16(u0, u1); H.v[1] = pack_hi16(u2, u3);
  H.v[2] = pack_hi16(u4, u5); H.v[3] = pack_hi16(u6, u7);
  L.v[0] = pack_hi16(r0, r1); L.v[1] = pack_hi16(r2, r3);
  L.v[2] = pack_hi16(r4, r5); L.v[3] = pack_hi16(r6, r7);
  Frag2 o; o.hi = H.f; o.lo = L.f; return o;
}

// Grid: 512 blocks = qq*64 + c (qq 0..7, 4 batches each). blockIdx%8 = c%8 ->
// all 8 qq-blocks of a channel share one XCD's L2 for the redundant weight
// reads. 2 blocks/CU (proven in R6) hides the per-wave latency chains that
// left R2 77% idle at 1 block/CU.
// Block: 512 threads = 8 waves; frag-row map (g=frag_n&3, i=4w+(frag_n>>2))
// puts all 4 gates of output i in one lane's acc[0..3] (no gate exchange).
// Weight delivery: R2's proven global_load_lds ring with COUNTED vmcnt (never
// 0 in-loop), depth 2 (64 KB) so two blocks fit per CU. Per-step schedule:
//   lgkmcnt(0)+barrier -> issue DMAs(t+1) -> vmcnt(4|5) -> compute(t)
// keeps a full step of prefetch distance with one barrier per step.
__global__ void __launch_bounds__(512, 4)
lstm_kernel(const float* __restrict__ x, const float* __restrict__ xOps,
            const float* __restrict__ hOps, float* __restrict__ out) {
  // Weights fp32: [slot][plane 0=xOps,1=hOps][row=g*32+i][32 floats]; 16B slots
  // within a row XOR-swizzled by f(row)=((g<<1)|(i&1)) applied on the per-lane
  // GLOBAL source (DMA dest stays linear), XOR-undone on the read side.
  __shared__ __align__(16) float Afp[2][2][128][32];   // 64 KiB
  __shared__ __align__(16) float Bx[2][16][32];        // 4 KiB; rows 8..15 = 0
  __shared__ __align__(16) short Hhi[2][16][HS];       // 2.5 KiB; rows 4..15 = 0
  __shared__ __align__(16) short Hlo[2][16][HS];       // 2.5 KiB
  __shared__ __align__(16) float Scr[256];             // 1 KiB dummy-DMA sink

  const int tid    = threadIdx.x;
  const int c      = blockIdx.x & 63;
  const int qq     = blockIdx.x >> 6;     // batch-eighth (4 batches)
  const int w      = tid >> 6;
  const int lane   = tid & 63;
  const int frag_n = lane & 15;           // batch col (valid < 4)
  const int quad   = lane >> 4;

  // ---- weight staging: 4 x global_load_lds (1 KiB = 8 rows) per wave ----
  int apl[4], arb[4];
  const float* aptr[4];
#pragma unroll
  for (int ii = 0; ii < 4; ++ii) {
    const int idx = w + 8 * ii;            // 32 chunks cover both planes
    const int pl  = idx >> 4;
    const int rb  = idx & 15;
    apl[ii] = pl; arb[ii] = rb;
    const int r    = rb * 8 + (lane >> 3); // LDS row = g*32+i
    const int g    = r >> 5;
    const int i    = r & 31;
    const int f    = ((r >> 5) << 1) | (r & 1);
    const int slot = (lane & 7) ^ f;       // pre-swizzled source slot
    const float* base = pl ? hOps : xOps;
    aptr[ii] = base + ((size_t)g * T_STEPS * C_CH + c) * 1024
                    + (size_t)i * 32 + slot * 4;
  }

  // ---- x staging (wave 7): 1 KiB DMA; rows 4..7 duplicate batches 0..3 (pad
  // cols only); source slot pre-swizzled by ^(row&7), read side XORs it back.
  const int xrow = lane >> 3;
  const float* xsrc = x + ((size_t)(qq * 4 + (xrow & 3)) * T_STEPS * C_CH + c) * 32
                        + (((lane & 7) ^ (xrow & 7)) << 2);
  const float* dummy_src = xOps;

  // Zero Bx (rows 8..15 stay 0) + H planes (h(0)=0; rows 4..15 stay 0).
  for (int idx = tid; idx < 2 * 16 * 32; idx += 512) ((float*)Bx)[idx] = 0.f;
  for (int idx = tid; idx < (2 * 16 * HS) / 2; idx += 512) {
    ((uint32_t*)Hhi)[idx] = 0u; ((uint32_t*)Hlo)[idx] = 0u;
  }
  __syncthreads();

  // ---- prologue: issue step 0 into slot 0 ----
#pragma unroll
  for (int ii = 0; ii < 4; ++ii) {
    async_load16(aptr[ii], &Afp[0][apl[ii]][arb[ii] * 8][0]);
    aptr[ii] += (size_t)C_CH * 1024;
  }
  if (w == 7) { async_load16(xsrc, &Bx[0][0][0]); xsrc += (size_t)C_CH * 32; }

  // ---- per-lane read constants (verbatim from verified R2 kernel) ----
  const int frow = (frag_n & 3) * 32 + 4 * w + (frag_n >> 2);
  const int ff   = ((frow >> 5) << 1) | (frow & 1);
  const int so0  = (((quad << 1) ^ ff) << 2);
  const int so1  = ((((quad << 1) | 1) ^ ff) << 2);
  const int bs0  = (((quad << 1) ^ (frag_n & 7)) << 2);
  const int bs1  = ((((quad << 1) | 1) ^ (frag_n & 7)) << 2);
  const int hrd  = quad * 8;
  const int iq   = 4 * w + quad;
  float c_state = 0.0f;

#define STEP(T, PAR)                                                            \
  do {                                                                          \
    /* h(t-1) visible; every wave's prior-step LDS reads drained (WAR-safe) */  \
    asm volatile("s_waitcnt lgkmcnt(0)\n\ts_barrier" ::: "memory");             \
    if ((T) + 1 < T_STEPS) {                                                    \
      _Pragma("unroll")                                                         \
      for (int ii = 0; ii < 4; ++ii) {                                          \
        async_load16(aptr[ii], &Afp[(PAR) ^ 1][apl[ii]][arb[ii] * 8][0]);       \
        aptr[ii] += (size_t)C_CH * 1024;                                        \
      }                                                                         \
      if (w == 7) {                                                             \
        async_load16(xsrc, &Bx[(PAR) ^ 1][0][0]);                               \
        xsrc += (size_t)C_CH * 32;                                              \
      }                                                                         \
    } else {                                                                    \
      _Pragma("unroll")                                                         \
      for (int ii = 0; ii < 4; ++ii) async_load16(dummy_src, &Scr[0]);          \
      if (w == 7) async_load16(dummy_src, &Scr[0]);                             \
    }                                                                           \
    /* counted wait: T's loads (issued a full step ago) done; T+1's 4|5 stay */ \
    if (w == 7) asm volatile("s_waitcnt vmcnt(5)" ::: "memory");                \
    else        asm volatile("s_waitcnt vmcnt(4)" ::: "memory");                \
    __builtin_amdgcn_sched_barrier(0);                                          \
    const float* Ap0 = &Afp[PAR][0][frow][0];                                   \
    Frag2 A0 = split8(*(const float4*)(Ap0 + so0), *(const float4*)(Ap0 + so1));\
    const float* Ap1 = &Afp[PAR][1][frow][0];                                   \
    Frag2 A1 = split8(*(const float4*)(Ap1 + so0), *(const float4*)(Ap1 + so1));\
    const float* Bp = &Bx[PAR][frag_n][0];                                      \
    Frag2 BX = split8(*(const float4*)(Bp + bs0), *(const float4*)(Bp + bs1));  \
    frag_cd ax = {0.f, 0.f, 0.f, 0.f};                                          \
    ax = __builtin_amdgcn_mfma_f32_16x16x32_bf16(A0.hi, BX.hi, ax, 0, 0, 0);    \
    ax = __builtin_amdgcn_mfma_f32_16x16x32_bf16(A0.hi, BX.lo, ax, 0, 0, 0);    \
    ax = __builtin_amdgcn_mfma_f32_16x16x32_bf16(A0.lo, BX.hi, ax, 0, 0, 0);    \
    const frag_ab bh = *(const frag_ab*)&Hhi[PAR][frag_n][hrd];                 \
    const frag_ab bl = *(const frag_ab*)&Hlo[PAR][frag_n][hrd];                 \
    frag_cd ah = {0.f, 0.f, 0.f, 0.f};                                          \
    ah = __builtin_amdgcn_mfma_f32_16x16x32_bf16(A1.hi, bh, ah, 0, 0, 0);       \
    ah = __builtin_amdgcn_mfma_f32_16x16x32_bf16(A1.hi, bl, ah, 0, 0, 0);       \
    ah = __builtin_amdgcn_mfma_f32_16x16x32_bf16(A1.lo, bh, ah, 0, 0, 0);       \
    const float ig = fast_sigmoid(ax[0] + ah[0]);                               \
    const float fg = fast_sigmoid(ax[1] + ah[1]);                               \
    const float gg = fast_tanh(ax[2] + ah[2]);                                  \
    const float og = fast_sigmoid(ax[3] + ah[3]);                               \
    c_state = fg * c_state + ig * gg;                                           \
    const float hval = og * fast_tanh(c_state);                                 \
    if ((T) == T_STEPS - 1) {                                                   \
      if (frag_n < 4)                                                           \
        out[((size_t)(qq * 4 + frag_n) * C_CH + c) * 32 + iq] = hval;           \
    } else if (frag_n < 4) {                                                    \
      const uint32_t uh = __float_as_uint(hval);                                \
      const float    rh = hval - __uint_as_float(uh & 0xFFFF0000u);             \
      Hhi[(PAR) ^ 1][frag_n][iq] = (short)(uh >> 16);                           \
      Hlo[(PAR) ^ 1][frag_n][iq] = (short)(__float_as_uint(rh) >> 16);          \
    }                                                                           \
  } while (0)

  for (int tb = 0; tb < T_STEPS; tb += 2) {
    STEP(tb,     0);
    STEP(tb + 1, 1);
  }
#undef STEP
}

extern "C" void kernel_launch(void* const* d_in, const int* in_sizes, int n_in,
                              void* d_out, int out_size, void* d_ws, size_t ws_size,
                              hipStream_t stream) {
  const float* x    = (const float*)d_in[0];
  const float* xOps = (const float*)d_in[1];
  const float* hOps = (const float*)d_in[2];
  lstm_kernel<<<dim3(512), dim3(512), 0, stream>>>(x, xOps, hOps, (float*)d_out);
}